// Round 7
// baseline (192.535 us; speedup 1.0000x reference)
//
#include <hip/hip_runtime.h>
#include <hip/hip_bf16.h>

// DeConv2d = 32 per-channel MLPs (128->256->256->4) over 8192 px + 2x2 shuffle.
//
// R7: R6 showed all pipes <20% busy at 125us vs ~25us floors -> overlap failure.
// Structure kept (4 waves, nf=4, LDS 48K, 3 blocks/CU); changes:
//  - 2 items (2x64 px) per block, grid 2048: item-1 pix staged into the dead
//    pix region right after B1(item0) -> stage hides under layer 2
//  - unified wvA/B/C weight rotation W1->W2->W1' that never drains across phases
//  - s_setprio(1) around MFMA clusters (phase-diverse blocks on each CU)
//
// Workspace: pix [8192][128] bf16 @0; W1t [32][256][128] @2MB; W2t [32][256][256] @4MB;
//            W3t [32][16][256] @8MB (rows 4..15 zero).

#define IC    128
#define IHW   1024
#define OCH   32
#define HDIM  256

typedef float  f32x4  __attribute__((ext_vector_type(4)));
typedef float  f32x2  __attribute__((ext_vector_type(2)));
typedef __bf16 bf16x8 __attribute__((ext_vector_type(8)));
typedef unsigned short us8 __attribute__((ext_vector_type(8)));
typedef unsigned int u32;

static __device__ __forceinline__ unsigned short f2bf(float f) {
  __hip_bfloat16 h = __float2bfloat16(f);
  return __builtin_bit_cast(unsigned short, h);
}

static __device__ __forceinline__ bf16x8 ld16(const unsigned short* p) {
  return __builtin_bit_cast(bf16x8, *reinterpret_cast<const uint4*>(p));
}

static __device__ __forceinline__ void gl_lds16(const unsigned short* g, char* l) {
  __builtin_amdgcn_global_load_lds(
      (const __attribute__((address_space(1))) u32*)g,
      (__attribute__((address_space(3))) u32*)l,
      16, 0, 0);
}

// ---- coalesced transpose prepass: dst[b][c][r] (bf16) = src[b][r][c] (f32) ----
__global__ __launch_bounds__(256) void transpose_bf16_k(
    const float* __restrict__ src, unsigned short* __restrict__ dst,
    int NR, int NC, int nrt, int nct)
{
  __shared__ float tl[64 * 65];
  const int bid = blockIdx.x;
  const int ct = bid % nct;
  const int rt = (bid / nct) % nrt;
  const int b  = bid / (nct * nrt);
  const int t  = threadIdx.x;

  const float* sb = src + ((size_t)b * NR + (rt << 6)) * NC + (ct << 6);
  const int col = (t & 15) << 2;
  const int rq  = t >> 4;
#pragma unroll
  for (int rr = 0; rr < 4; ++rr) {
    int row = (rr << 4) + rq;
    f32x4 v = *reinterpret_cast<const f32x4*>(sb + row * NC + col);
#pragma unroll
    for (int i = 0; i < 4; ++i) tl[row * 65 + col + i] = v[i];
  }
  __syncthreads();

  unsigned short* db = dst + ((size_t)b * NC + (ct << 6)) * NR + (rt << 6);
  const int r0 = (t & 7) << 3;
  const int cq = t >> 3;
#pragma unroll
  for (int cr = 0; cr < 2; ++cr) {
    int c = (cr << 5) + cq;
    us8 vv;
#pragma unroll
    for (int i = 0; i < 8; ++i) vv[i] = f2bf(tl[(r0 + i) * 65 + c]);
    *reinterpret_cast<us8*>(db + (size_t)c * NR + r0) = vv;
  }
}

__global__ void conv_w3_k(const float* __restrict__ W3, unsigned short* __restrict__ W3t) {
  int idx = blockIdx.x * 256 + threadIdx.x;
  int k = idx & 255;
  int nn = (idx >> 8) & 15;
  int o = idx >> 12;
  W3t[idx] = (nn < 4) ? f2bf(W3[(o * HDIM + k) * 4 + nn]) : (unsigned short)0;
}

// ---- fused 3-layer MLP ----
// Block = 256 thr = 4 waves, (group o, 2 items of 64 px). Wave w owns n-rows
// [w*64, w*64+64) (nf=4). D frag: col=lane&15 -> px, row=(lane>>4)*4+reg -> n.
// LDS: pix 16KB @0 (single buf, re-staged per item); h 32KB @16384. Swz ^((m&7)<<4).

#define LD_B_PIX(dst, ks)                                                        \
  _Pragma("unroll")                                                              \
  for (int mf = 0; mf < 4; ++mf) {                                               \
    int m = (mf << 4) + l15;                                                     \
    dst[mf] = *reinterpret_cast<const bf16x8*>(                                  \
        pb + ((((m << 8) + ((ks) << 6) + (kgrp << 1))) ^ ((m & 7) << 4)));       \
  }

#define LD_B_H(dst, ks)                                                          \
  _Pragma("unroll")                                                              \
  for (int mf = 0; mf < 4; ++mf) {                                               \
    int m = (mf << 4) + l15;                                                     \
    dst[mf] = *reinterpret_cast<const bf16x8*>(                                  \
        hb + ((((m << 9) + ((ks) << 6) + (kgrp << 1))) ^ ((m & 7) << 4)));       \
  }

#define LD_W1(dst, ks)                                                           \
  _Pragma("unroll")                                                              \
  for (int nf = 0; nf < 4; ++nf) dst[nf] = ld16(W1p + (nf << 4) * IC + ((ks) << 5));

#define LD_W2(dst, ks)                                                           \
  _Pragma("unroll")                                                              \
  for (int nf = 0; nf < 4; ++nf) dst[nf] = ld16(W2p + (nf << 4) * HDIM + ((ks) << 5));

#define MFMA16(WV, BP)                                                           \
  __builtin_amdgcn_s_setprio(1);                                                 \
  _Pragma("unroll")                                                              \
  for (int nf = 0; nf < 4; ++nf)                                                 \
    _Pragma("unroll")                                                            \
    for (int mf = 0; mf < 4; ++mf)                                               \
      acc[nf][mf] = __builtin_amdgcn_mfma_f32_16x16x32_bf16(WV[nf], BP[mf], acc[nf][mf], 0, 0, 0); \
  __builtin_amdgcn_s_setprio(0);

#define EPILOGUE(bias, region)                                                   \
  _Pragma("unroll")                                                              \
  for (int nf = 0; nf < 4; ++nf) {                                               \
    int n0 = wnb + (nf << 4) + (lg << 2);                                        \
    f32x4 bb = *reinterpret_cast<const f32x4*>((bias) + n0);                     \
    _Pragma("unroll")                                                            \
    for (int mf = 0; mf < 4; ++mf) {                                             \
      int m = (mf << 4) + l15;                                                   \
      ushort4 hv;                                                                \
      hv.x = f2bf(fmaxf(acc[nf][mf][0] + bb[0], 0.f));                           \
      hv.y = f2bf(fmaxf(acc[nf][mf][1] + bb[1], 0.f));                           \
      hv.z = f2bf(fmaxf(acc[nf][mf][2] + bb[2], 0.f));                           \
      hv.w = f2bf(fmaxf(acc[nf][mf][3] + bb[3], 0.f));                           \
      *reinterpret_cast<ushort4*>(                                               \
          (region) + (((m << 9) + (n0 << 1)) ^ ((m & 7) << 4))) = hv;            \
    }                                                                            \
  }

#define ZERO_ACC                                                                 \
  _Pragma("unroll")                                                              \
  for (int nf = 0; nf < 4; ++nf)                                                 \
    _Pragma("unroll")                                                            \
    for (int mf = 0; mf < 4; ++mf) acc[nf][mf] = vzero;

__global__ __launch_bounds__(256, 3) void fused_mlp_k(
    const unsigned short* __restrict__ pix,
    const unsigned short* __restrict__ W1t,
    const unsigned short* __restrict__ W2t,
    const unsigned short* __restrict__ W3t,
    const float* __restrict__ b1,
    const float* __restrict__ b2,
    const float* __restrict__ b3f,
    float* __restrict__ out)
{
  __shared__ __align__(16) char lds[49152];
  const int t    = threadIdx.x;
  const int lane = t & 63;
  const int w    = t >> 6;                          // 0..3
  const int bx   = blockIdx.x;
  const int o    = ((bx & 7) << 2) | ((bx >> 3) & 3);   // 4 groups per XCD
  const int pixbase = (bx >> 5) << 7;               // 128 px per block (2 items)

  const int l15  = lane & 15;
  const int lg   = lane >> 4;
  const int kgrp = lg << 3;
  const int wnb  = w << 6;

  char* pb = lds;
  char* hb = lds + 16384;

  // ---- prologue: stage item-0 pix; preload W1 ks0-2 into the rotation ----
#pragma unroll
  for (int r = 0; r < 4; ++r) {
    int slot = (r << 8) + t;
    int m = slot >> 4, j = slot & 15;
    gl_lds16(pix + (size_t)(pixbase + m) * IC + ((j ^ (m & 7)) << 3),
             pb + (((r << 8) + (w << 6)) << 4));
  }

  const unsigned short* W1p = W1t + (o << 15) + (wnb + l15) * IC + kgrp;
  const unsigned short* W2p = W2t + (o << 16) + (wnb + l15) * HDIM + kgrp;
  const float* b1o = b1 + (o << 8);
  const float* b2o = b2 + (o << 8);
  const f32x4 vzero = {0.f, 0.f, 0.f, 0.f};

  bf16x8 wvA[4], wvB[4], wvC[4], bp[4], bq[4];
  LD_W1(wvA, 0) LD_W1(wvB, 1) LD_W1(wvC, 2)

  f32x4 acc[4][4];
  ZERO_ACC

  __syncthreads();   // B0: pix item-0 ready

#pragma unroll
  for (int it = 0; it < 2; ++it) {
    // ================= layer 1: K=128 (ks 0-3), rotation A,B,C,A ==============
    // entering: wvA=W1ks0, wvB=W1ks1, wvC=W1ks2
    LD_B_PIX(bp, 0)
    LD_B_PIX(bq, 1) MFMA16(wvA, bp) LD_W1(wvA, 3)
    LD_B_PIX(bp, 2) MFMA16(wvB, bq) LD_W2(wvB, 0)
    LD_B_PIX(bq, 3) MFMA16(wvC, bp) LD_W2(wvC, 1)
                    MFMA16(wvA, bq) LD_W2(wvA, 2)

    EPILOGUE(b1o, hb)
    __syncthreads();   // B1: h1 visible; pix item reads all done

    // stage item-1 pix into the (now dead) pix region; drains at B2
    if (it == 0) {
#pragma unroll
      for (int r = 0; r < 4; ++r) {
        int slot = (r << 8) + t;
        int m = slot >> 4, j = slot & 15;
        gl_lds16(pix + (size_t)(pixbase + 64 + m) * IC + ((j ^ (m & 7)) << 3),
                 pb + (((r << 8) + (w << 6)) << 4));
      }
    }

    ZERO_ACC

    // ================= layer 2: K=256 (ks 0-7), rotation B,C,A,B,C,A,B,C ======
    // entering: wvB=W2ks0, wvC=W2ks1, wvA=W2ks2
    LD_B_H(bp, 0)
    LD_B_H(bq, 1) MFMA16(wvB, bp) LD_W2(wvB, 3)
    LD_B_H(bp, 2) MFMA16(wvC, bq) LD_W2(wvC, 4)
    LD_B_H(bq, 3) MFMA16(wvA, bp) LD_W2(wvA, 5)
    LD_B_H(bp, 4) MFMA16(wvB, bq) LD_W2(wvB, 6)
    LD_B_H(bq, 5) MFMA16(wvC, bp) LD_W2(wvC, 7)
    LD_B_H(bp, 6) MFMA16(wvA, bq) LD_W1(wvA, 0)   // refill for next item's L1
    LD_B_H(bq, 7) MFMA16(wvB, bp) LD_W1(wvB, 1)
                  MFMA16(wvC, bq) LD_W1(wvC, 2)

    __syncthreads();   // B2: all h1 reads done (+ item-1 pix stage drained)

    EPILOGUE(b2o, hb)  // h2 overwrites h1 region
    __syncthreads();   // B3: h2 visible

    // ================= layer 3: wave w owns px [w*16, w*16+16), full K ========
    {
      f32x4 acc3 = vzero;
      const unsigned short* W3p = W3t + (o << 12) + l15 * HDIM + kgrp;
      const int m3 = (w << 4) + l15;
      bf16x8 w3c = ld16(W3p);
      bf16x8 bh = *reinterpret_cast<const bf16x8*>(
          hb + (((m3 << 9) + (kgrp << 1)) ^ ((m3 & 7) << 4)));
#pragma unroll
      for (int ks = 0; ks < 8; ++ks) {
        bf16x8 w3n, bn;
        if (ks < 7) {
          w3n = ld16(W3p + ((ks + 1) << 5));
          bn = *reinterpret_cast<const bf16x8*>(
              hb + (((m3 << 9) + ((ks + 1) << 6) + (kgrp << 1)) ^ ((m3 & 7) << 4)));
        }
        __builtin_amdgcn_s_setprio(1);
        acc3 = __builtin_amdgcn_mfma_f32_16x16x32_bf16(w3c, bh, acc3, 0, 0, 0);
        __builtin_amdgcn_s_setprio(0);
        w3c = w3n; bh = bn;
      }
      if (lane < 16) {
        int pixel = pixbase + (it << 6) + m3;
        int n = pixel >> 10, p = pixel & 1023;
        int ii = p >> 5, jj = p & 31;
        float* ob = out + ((size_t)((n << 5) + o) << 12) + (ii << 7) + (jj << 1);
        f32x2 r0 = { acc3[0] + b3f[(o << 2) + 0], acc3[1] + b3f[(o << 2) + 1] };
        f32x2 r1 = { acc3[2] + b3f[(o << 2) + 2], acc3[3] + b3f[(o << 2) + 3] };
        *reinterpret_cast<f32x2*>(ob) = r0;
        *reinterpret_cast<f32x2*>(ob + 64) = r1;
      }
    }
    __syncthreads();   // B4: h2 reads done; next item may overwrite hb

    if (it == 0) { ZERO_ACC }
  }
}

extern "C" void kernel_launch(void* const* d_in, const int* in_sizes, int n_in,
                              void* d_out, int out_size, void* d_ws, size_t ws_size,
                              hipStream_t stream) {
  const float* x  = (const float*)d_in[0];
  const float* W1 = (const float*)d_in[1];
  const float* b1 = (const float*)d_in[2];
  const float* W2 = (const float*)d_in[3];
  const float* b2 = (const float*)d_in[4];
  const float* W3 = (const float*)d_in[5];
  const float* b3 = (const float*)d_in[6];
  float* out = (float*)d_out;

  char* ws = (char*)d_ws;
  unsigned short* pixw = (unsigned short*)(ws);
  unsigned short* W1t  = (unsigned short*)(ws + (size_t)(2u << 20));
  unsigned short* W2t  = (unsigned short*)(ws + (size_t)(4u << 20));
  unsigned short* W3t  = (unsigned short*)(ws + (size_t)(8u << 20));

  transpose_bf16_k<<<8 * 2 * 16, 256, 0, stream>>>(x, pixw, 128, 1024, 2, 16);
  transpose_bf16_k<<<32 * 2 * 4, 256, 0, stream>>>(W1, W1t, 128, 256, 2, 4);
  transpose_bf16_k<<<32 * 4 * 4, 256, 0, stream>>>(W2, W2t, 256, 256, 4, 4);
  conv_w3_k<<<512, 256, 0, stream>>>(W3, W3t);

  fused_mlp_k<<<2048, 256, 0, stream>>>(pixw, W1t, W2t, W3t, b1, b2, b3, out);
}

// Round 8
// 122.996 us; speedup vs baseline: 1.5654x; 1.5654x over previous
//
#include <hip/hip_runtime.h>
#include <hip/hip_bf16.h>

// DeConv2d = 32 per-channel MLPs (128->256->256->4) over 8192 px + 2x2 shuffle.
//
// R8: register-cap analysis: launch_bounds(256,3) => 170 total regs incl AGPR;
// R6 saturates it; R5/R7 deep pipelines spilled (~550MB scratch signature).
// Best clean config = R4 (resident weights, 2 waves/SIMD). R8 = R4 minus its
// stalls: 8-wave block, nf=2, W1+W2 resident (loads only in prologue),
// grid 2048 x 2 tiles, LDS 48KB, 4 barriers/tile, L3 full-K on waves 0-3
// with dual accumulators (no K-split exchange), pix restage hidden under L2.
//
// Workspace: pix [8192][128] bf16 @0; W1t [32][256][128] @2MB; W2t [32][256][256] @4MB;
//            W3t [32][16][256] @8MB (rows 4..15 zero).

#define IC    128
#define IHW   1024
#define OCH   32
#define HDIM  256

typedef float  f32x4  __attribute__((ext_vector_type(4)));
typedef float  f32x2  __attribute__((ext_vector_type(2)));
typedef __bf16 bf16x8 __attribute__((ext_vector_type(8)));
typedef unsigned short us8 __attribute__((ext_vector_type(8)));
typedef unsigned int u32;

static __device__ __forceinline__ unsigned short f2bf(float f) {
  __hip_bfloat16 h = __float2bfloat16(f);
  return __builtin_bit_cast(unsigned short, h);
}

static __device__ __forceinline__ bf16x8 ld16(const unsigned short* p) {
  return __builtin_bit_cast(bf16x8, *reinterpret_cast<const uint4*>(p));
}

static __device__ __forceinline__ void gl_lds16(const unsigned short* g, char* l) {
  __builtin_amdgcn_global_load_lds(
      (const __attribute__((address_space(1))) u32*)g,
      (__attribute__((address_space(3))) u32*)l,
      16, 0, 0);
}

// ---- coalesced transpose prepass: dst[b][c][r] (bf16) = src[b][r][c] (f32) ----
__global__ __launch_bounds__(256) void transpose_bf16_k(
    const float* __restrict__ src, unsigned short* __restrict__ dst,
    int NR, int NC, int nrt, int nct)
{
  __shared__ float tl[64 * 65];
  const int bid = blockIdx.x;
  const int ct = bid % nct;
  const int rt = (bid / nct) % nrt;
  const int b  = bid / (nct * nrt);
  const int t  = threadIdx.x;

  const float* sb = src + ((size_t)b * NR + (rt << 6)) * NC + (ct << 6);
  const int col = (t & 15) << 2;
  const int rq  = t >> 4;
#pragma unroll
  for (int rr = 0; rr < 4; ++rr) {
    int row = (rr << 4) + rq;
    f32x4 v = *reinterpret_cast<const f32x4*>(sb + row * NC + col);
#pragma unroll
    for (int i = 0; i < 4; ++i) tl[row * 65 + col + i] = v[i];
  }
  __syncthreads();

  unsigned short* db = dst + ((size_t)b * NC + (ct << 6)) * NR + (rt << 6);
  const int r0 = (t & 7) << 3;
  const int cq = t >> 3;
#pragma unroll
  for (int cr = 0; cr < 2; ++cr) {
    int c = (cr << 5) + cq;
    us8 vv;
#pragma unroll
    for (int i = 0; i < 8; ++i) vv[i] = f2bf(tl[(r0 + i) * 65 + c]);
    *reinterpret_cast<us8*>(db + (size_t)c * NR + r0) = vv;
  }
}

__global__ void conv_w3_k(const float* __restrict__ W3, unsigned short* __restrict__ W3t) {
  int idx = blockIdx.x * 256 + threadIdx.x;
  int k = idx & 255;
  int nn = (idx >> 8) & 15;
  int o = idx >> 12;
  W3t[idx] = (nn < 4) ? f2bf(W3[(o * HDIM + k) * 4 + nn]) : (unsigned short)0;
}

// ---- fused 3-layer MLP ----
// Block = 512 thr = 8 waves, (group o, 2 tiles of 64 px). Wave w owns n-rows
// [w*32, w*32+32) for layers 1-2 (nf=2), weights RESIDENT in VGPR.
// D frag: col=lane&15 -> px, row=(lane>>4)*4+reg -> n.
// LDS: pix 16KB @0 (single buf, restaged); h 32KB @16384 (h1 then h2). Swz ^((m&7)<<4).

#define LD_B_PIX(dst, ks)                                                        \
  _Pragma("unroll")                                                              \
  for (int mf = 0; mf < 4; ++mf) {                                               \
    int m = (mf << 4) + l15;                                                     \
    dst[mf] = *reinterpret_cast<const bf16x8*>(                                  \
        pb + ((((m << 8) + ((ks) << 6) + (kgrp << 1))) ^ ((m & 7) << 4)));       \
  }

#define LD_B_H(dst, ks)                                                          \
  _Pragma("unroll")                                                              \
  for (int mf = 0; mf < 4; ++mf) {                                               \
    int m = (mf << 4) + l15;                                                     \
    dst[mf] = *reinterpret_cast<const bf16x8*>(                                  \
        hb + ((((m << 9) + ((ks) << 6) + (kgrp << 1))) ^ ((m & 7) << 4)));       \
  }

#define MFMA8(WR, KS, BP)                                                        \
  _Pragma("unroll")                                                              \
  for (int nf = 0; nf < 2; ++nf)                                                 \
    _Pragma("unroll")                                                            \
    for (int mf = 0; mf < 4; ++mf)                                               \
      acc[nf][mf] = __builtin_amdgcn_mfma_f32_16x16x32_bf16(WR[nf][KS], BP[mf], acc[nf][mf], 0, 0, 0);

#define EPILOGUE(bias)                                                           \
  _Pragma("unroll")                                                              \
  for (int nf = 0; nf < 2; ++nf) {                                               \
    int n0 = wnb + (nf << 4) + (lg << 2);                                        \
    f32x4 bb = *reinterpret_cast<const f32x4*>((bias) + n0);                     \
    _Pragma("unroll")                                                            \
    for (int mf = 0; mf < 4; ++mf) {                                             \
      int m = (mf << 4) + l15;                                                   \
      ushort4 hv;                                                                \
      hv.x = f2bf(fmaxf(acc[nf][mf][0] + bb[0], 0.f));                           \
      hv.y = f2bf(fmaxf(acc[nf][mf][1] + bb[1], 0.f));                           \
      hv.z = f2bf(fmaxf(acc[nf][mf][2] + bb[2], 0.f));                           \
      hv.w = f2bf(fmaxf(acc[nf][mf][3] + bb[3], 0.f));                           \
      *reinterpret_cast<ushort4*>(                                               \
          hb + (((m << 9) + (n0 << 1)) ^ ((m & 7) << 4))) = hv;                  \
    }                                                                            \
  }

#define ZERO_ACC                                                                 \
  _Pragma("unroll")                                                              \
  for (int nf = 0; nf < 2; ++nf)                                                 \
    _Pragma("unroll")                                                            \
    for (int mf = 0; mf < 4; ++mf) acc[nf][mf] = vzero;

#define LDH3(ks)                                                                 \
  (*reinterpret_cast<const bf16x8*>(                                             \
      hb + (((m3 << 9) + ((ks) << 6) + (kgrp << 1)) ^ ((m3 & 7) << 4))))

__global__ __launch_bounds__(512, 2) void fused_mlp_k(
    const unsigned short* __restrict__ pix,
    const unsigned short* __restrict__ W1t,
    const unsigned short* __restrict__ W2t,
    const unsigned short* __restrict__ W3t,
    const float* __restrict__ b1,
    const float* __restrict__ b2,
    const float* __restrict__ b3f,
    float* __restrict__ out)
{
  __shared__ __align__(16) char lds[49152];
  const int t    = threadIdx.x;
  const int lane = t & 63;
  const int w    = t >> 6;                          // 0..7
  const int bx   = blockIdx.x;
  const int o    = ((bx & 7) << 2) | ((bx >> 3) & 3);   // 4 groups per XCD
  const int pixbase = (bx >> 5) << 7;               // 128 px per block (2 tiles)

  const int l15  = lane & 15;
  const int lg   = lane >> 4;
  const int kgrp = lg << 3;
  const int wnb  = w << 5;                          // wave's 32-row n-slice

  char* pb = lds;
  char* hb = lds + 16384;

  // ---- stage tile-0 pix (async; drains at B0) ----
#pragma unroll
  for (int r = 0; r < 2; ++r) {
    int slot = (r << 9) + t;
    int m = slot >> 4, j = slot & 15;
    gl_lds16(pix + (size_t)(pixbase + m) * IC + ((j ^ (m & 7)) << 3),
             pb + slot * 16);
  }

  // ---- resident weights (prologue only; K-loops have ZERO global loads) ----
  const unsigned short* W1p = W1t + (o << 15) + (wnb + l15) * IC + kgrp;
  const unsigned short* W2p = W2t + (o << 16) + (wnb + l15) * HDIM + kgrp;
  bf16x8 W1r[2][4], W2r[2][8];
#pragma unroll
  for (int nf = 0; nf < 2; ++nf)
#pragma unroll
    for (int ks = 0; ks < 4; ++ks)
      W1r[nf][ks] = ld16(W1p + (nf << 4) * IC + (ks << 5));
#pragma unroll
  for (int nf = 0; nf < 2; ++nf)
#pragma unroll
    for (int ks = 0; ks < 8; ++ks)
      W2r[nf][ks] = ld16(W2p + (nf << 4) * HDIM + (ks << 5));

  const float* b1o = b1 + (o << 8);
  const float* b2o = b2 + (o << 8);
  const f32x4 vzero = {0.f, 0.f, 0.f, 0.f};

  f32x4 acc[2][4];
  bf16x8 bp[4], bq[4];

  __syncthreads();   // B0: tile-0 pix ready

#pragma unroll
  for (int tt = 0; tt < 2; ++tt) {
    const int base = pixbase + (tt << 6);

    // ================= layer 1: K=128, resident W1 =================
    ZERO_ACC
    LD_B_PIX(bp, 0)
    LD_B_PIX(bq, 1) MFMA8(W1r, 0, bp)
    LD_B_PIX(bp, 2) MFMA8(W1r, 1, bq)
    LD_B_PIX(bq, 3) MFMA8(W1r, 2, bp)
                    MFMA8(W1r, 3, bq)
    EPILOGUE(b1o)
    __syncthreads();   // B1: h1 ready; pix reads done

    // restage pix for tile 1 (issued under L2, drains at B2)
    if (tt == 0) {
#pragma unroll
      for (int r = 0; r < 2; ++r) {
        int slot = (r << 9) + t;
        int m = slot >> 4, j = slot & 15;
        gl_lds16(pix + (size_t)(pixbase + 64 + m) * IC + ((j ^ (m & 7)) << 3),
                 pb + slot * 16);
      }
    }

    // ================= layer 2: K=256, resident W2 =================
    ZERO_ACC
    LD_B_H(bp, 0)
    LD_B_H(bq, 1) MFMA8(W2r, 0, bp)
    LD_B_H(bp, 2) MFMA8(W2r, 1, bq)
    LD_B_H(bq, 3) MFMA8(W2r, 2, bp)
    LD_B_H(bp, 4) MFMA8(W2r, 3, bq)
    LD_B_H(bq, 5) MFMA8(W2r, 4, bp)
    LD_B_H(bp, 6) MFMA8(W2r, 5, bq)
    LD_B_H(bq, 7) MFMA8(W2r, 6, bp)
                  MFMA8(W2r, 7, bq)
    __syncthreads();   // B2: h1 reads done (+ restage drained)

    EPILOGUE(b2o)      // h2 overwrites h1 region
    __syncthreads();   // B3: h2 ready

    // ===== layer 3: waves 0-3, 16 px each, FULL K, dual accumulators =====
    if (w < 4) {
      const unsigned short* W3p = W3t + (o << 12) + l15 * HDIM + kgrp;
      const int m3 = (w << 4) + l15;
      f32x4 a3a = vzero, a3b = vzero;
      bf16x8 w3f0 = ld16(W3p),        w3f1 = ld16(W3p + 32);
      bf16x8 bh0  = LDH3(0),          bh1  = LDH3(1);
#pragma unroll
      for (int ks = 0; ks < 8; ks += 2) {
        bf16x8 wnA, bnA, wnB, bnB;
        if (ks < 6) {
          wnA = ld16(W3p + ((ks + 2) << 5));  bnA = LDH3(ks + 2);
          wnB = ld16(W3p + ((ks + 3) << 5));  bnB = LDH3(ks + 3);
        }
        a3a = __builtin_amdgcn_mfma_f32_16x16x32_bf16(w3f0, bh0, a3a, 0, 0, 0);
        a3b = __builtin_amdgcn_mfma_f32_16x16x32_bf16(w3f1, bh1, a3b, 0, 0, 0);
        w3f0 = wnA; bh0 = bnA; w3f1 = wnB; bh1 = bnB;
      }
      if (lane < 16) {
        int pixel = base + m3;
        int n = pixel >> 10, p = pixel & 1023;
        int ii = p >> 5, jj = p & 31;
        float* ob = out + ((size_t)((n << 5) + o) << 12) + (ii << 7) + (jj << 1);
        f32x2 r0 = { a3a[0] + a3b[0] + b3f[(o << 2) + 0],
                     a3a[1] + a3b[1] + b3f[(o << 2) + 1] };
        f32x2 r1 = { a3a[2] + a3b[2] + b3f[(o << 2) + 2],
                     a3a[3] + a3b[3] + b3f[(o << 2) + 3] };
        *reinterpret_cast<f32x2*>(ob) = r0;
        *reinterpret_cast<f32x2*>(ob + 64) = r1;
      }
    }
    if (tt == 0) __syncthreads();   // B4: h2 reads done; tile-1 may overwrite hb
  }
}

extern "C" void kernel_launch(void* const* d_in, const int* in_sizes, int n_in,
                              void* d_out, int out_size, void* d_ws, size_t ws_size,
                              hipStream_t stream) {
  const float* x  = (const float*)d_in[0];
  const float* W1 = (const float*)d_in[1];
  const float* b1 = (const float*)d_in[2];
  const float* W2 = (const float*)d_in[3];
  const float* b2 = (const float*)d_in[4];
  const float* W3 = (const float*)d_in[5];
  const float* b3 = (const float*)d_in[6];
  float* out = (float*)d_out;

  char* ws = (char*)d_ws;
  unsigned short* pixw = (unsigned short*)(ws);
  unsigned short* W1t  = (unsigned short*)(ws + (size_t)(2u << 20));
  unsigned short* W2t  = (unsigned short*)(ws + (size_t)(4u << 20));
  unsigned short* W3t  = (unsigned short*)(ws + (size_t)(8u << 20));

  transpose_bf16_k<<<8 * 2 * 16, 256, 0, stream>>>(x, pixw, 128, 1024, 2, 16);
  transpose_bf16_k<<<32 * 2 * 4, 256, 0, stream>>>(W1, W1t, 128, 256, 2, 4);
  transpose_bf16_k<<<32 * 4 * 4, 256, 0, stream>>>(W2, W2t, 256, 256, 4, 4);
  conv_w3_k<<<512, 256, 0, stream>>>(W3, W3t);

  fused_mlp_k<<<2048, 512, 0, stream>>>(pixw, W1t, W2t, W3t, b1, b2, b3, out);
}